// Round 4
// baseline (264.245 us; speedup 1.0000x reference)
//
#include <hip/hip_runtime.h>
#include <math.h>

#define ROWS 8192
#define NCOL 2048
#define V 32
#define WPB 4                 // waves (rows) per block
#define THREADS (WPB * 64)

// static compare-exchange: ascending, both indices compile-time
__device__ __forceinline__ void ce(float& a, float& b) {
  const float lo = fminf(a, b);
  const float hi = fmaxf(a, b);
  a = lo; b = hi;
}

// med3(a,b,-inf)=min(a,b); med3(a,b,+inf)=max(a,b). One VALU op per
// cross-lane compare-exchange, direction baked into per-pass constant.
__device__ __forceinline__ float ce_dir(float a, float b, float cdir) {
  return __builtin_amdgcn_fmed3f(a, b, cdir);
}

// ---- cross-lane partner fetch x[lane ^ M] ----
// ds_swizzle BitMode for all masks <= 31 (pattern is an immediate, zero VALU
// address overhead). Mask 63 uses ds_bpermute with an address VGPR computed
// once at entry.
template <int M>
__device__ __forceinline__ float lane_xor(float x, int a63) {
  if constexpr (M == 63) {
    return __builtin_bit_cast(
        float, __builtin_amdgcn_ds_bpermute(a63, __builtin_bit_cast(int, x)));
  } else {
    static_assert(M >= 1 && M <= 31, "swizzle mask");
    constexpr int pat = (M << 10) | 0x1F;  // BitMode: xor=M, or=0, and=0x1F
    return __builtin_bit_cast(
        float, __builtin_amdgcn_ds_swizzle(__builtin_bit_cast(int, x), pat));
  }
}

// cross-lane xor pass over both arrays, same element index, mask M.
// 16 independent DS ops in flight before the med3 batch.
template <int M>
__device__ __forceinline__ void xpass2(float (&a)[V], float (&b)[V],
                                       float cdir, int a63) {
#pragma unroll
  for (int c = 0; c < V; c += 8) {
    float oa[8], ob[8];
#pragma unroll
    for (int u = 0; u < 8; ++u) oa[u] = lane_xor<M>(a[c + u], a63);
#pragma unroll
    for (int u = 0; u < 8; ++u) ob[u] = lane_xor<M>(b[c + u], a63);
#pragma unroll
    for (int u = 0; u < 8; ++u) a[c + u] = ce_dir(a[c + u], oa[u], cdir);
#pragma unroll
    for (int u = 0; u < 8; ++u) b[c + u] = ce_dir(b[c + u], ob[u], cdir);
  }
}

// One bitonic merge stage for run length k = 64*KB (KB = 1..32):
// flip pass (partner lane^(2KB-1), elem v^31), xor passes KB/2..1,
// then the in-lane tail j = 16..1. Both arrays per pass for ILP.
template <int KB>
__device__ __forceinline__ void merge2(float (&a)[V], float (&b)[V],
                                       int lane, int a63) {
  {
    constexpr int LM = 2 * KB - 1;
    const float cdir = (lane & KB) ? INFINITY : -INFINITY;
#pragma unroll
    for (int q = 0; q < 4; ++q) {
      const int vA = 4 * q;
      float o[8];
#pragma unroll
      for (int u = 0; u < 4; ++u) {
        o[u]     = lane_xor<LM>(a[(vA + u) ^ 31], a63);
        o[u + 4] = lane_xor<LM>(a[vA + u], a63);
      }
#pragma unroll
      for (int u = 0; u < 4; ++u) {
        a[vA + u]        = ce_dir(a[vA + u],        o[u],     cdir);
        a[(vA + u) ^ 31] = ce_dir(a[(vA + u) ^ 31], o[u + 4], cdir);
      }
#pragma unroll
      for (int u = 0; u < 4; ++u) {
        o[u]     = lane_xor<LM>(b[(vA + u) ^ 31], a63);
        o[u + 4] = lane_xor<LM>(b[vA + u], a63);
      }
#pragma unroll
      for (int u = 0; u < 4; ++u) {
        b[vA + u]        = ce_dir(b[vA + u],        o[u],     cdir);
        b[(vA + u) ^ 31] = ce_dir(b[(vA + u) ^ 31], o[u + 4], cdir);
      }
    }
  }
  if constexpr (KB >= 32) {
    const float cd = (lane & 16) ? INFINITY : -INFINITY;
    xpass2<16>(a, b, cd, a63);
  }
  if constexpr (KB >= 16) {
    const float cd = (lane & 8) ? INFINITY : -INFINITY;
    xpass2<8>(a, b, cd, a63);
  }
  if constexpr (KB >= 8) {
    const float cd = (lane & 4) ? INFINITY : -INFINITY;
    xpass2<4>(a, b, cd, a63);
  }
  if constexpr (KB >= 4) {
    const float cd = (lane & 2) ? INFINITY : -INFINITY;
    xpass2<2>(a, b, cd, a63);
  }
  if constexpr (KB >= 2) {
    const float cd = (lane & 1) ? INFINITY : -INFINITY;
    xpass2<1>(a, b, cd, a63);
  }
  // in-lane xor passes j = 16..1: static indices AND static direction
#pragma unroll
  for (int j = 16; j >= 1; j >>= 1) {
#pragma unroll
    for (int v = 0; v < V; ++v) {
      if ((v & j) == 0) {
        ce(a[v], a[v | j]);
        ce(b[v], b[v | j]);
      }
    }
  }
}

// One wave per row; lane holds elements e = lane*32 + v of both arrays in
// registers. Normalized bitonic sort (all compares ascending).
//
// __launch_bounds__(THREADS, 2): the (THREADS, 4) variant capped the unified
// register budget at 128/wave, and the allocator split the 64 live floats
// across VGPRs+AGPRs (rocprof: VGPR_Count=40 < 64 live values, no scratch
// traffic) -> v_accvgpr_read/write round-trips around every cross-lane op,
// ~2x VALU inflation. A 256-reg budget keeps everything in plain VGPRs;
// HW occupancy at ~96 VGPRs is ~5 waves/SIMD, >= the measured 3.5.
__global__ __launch_bounds__(THREADS, 2) void sort_mse_kernel(
    const float* __restrict__ pred, const float* __restrict__ targ,
    float* __restrict__ out) {
  const int lane = threadIdx.x & 63;
  const int wave = threadIdx.x >> 6;
  const int row = blockIdx.x * WPB + wave;
  const size_t base = (size_t)row * NCOL + (size_t)lane * V;
  const int a63 = ((lane ^ 63) << 2);  // bpermute byte addr, computed once

  float rp[V], rt[V];
  const float4* p4 = (const float4*)(pred + base);
  const float4* t4 = (const float4*)(targ + base);
#pragma unroll
  for (int q = 0; q < V / 4; ++q) {
    const float4 a = p4[q];
    rp[4 * q + 0] = a.x; rp[4 * q + 1] = a.y;
    rp[4 * q + 2] = a.z; rp[4 * q + 3] = a.w;
    const float4 b = t4[q];
    rt[4 * q + 0] = b.x; rt[4 * q + 1] = b.y;
    rt[4 * q + 2] = b.z; rt[4 * q + 3] = b.w;
  }

  // ---- Phase 1: stages k = 2..32, fully in-lane, fully static ----
#pragma unroll
  for (int k = 2; k <= V; k <<= 1) {
#pragma unroll
    for (int v = 0; v < V; ++v) {
      if ((v & (k >> 1)) == 0) {
        ce(rp[v], rp[v ^ (k - 1)]);
        ce(rt[v], rt[v ^ (k - 1)]);
      }
    }
#pragma unroll
    for (int j = k >> 2; j >= 1; j >>= 1) {
#pragma unroll
      for (int v = 0; v < V; ++v) {
        if ((v & j) == 0) {
          ce(rp[v], rp[v | j]);
          ce(rt[v], rt[v | j]);
        }
      }
    }
  }

  // ---- Phase 2: stages k = 64..2048 (KB = k/64 = 1..32) ----
  merge2<1>(rp, rt, lane, a63);
  merge2<2>(rp, rt, lane, a63);
  merge2<4>(rp, rt, lane, a63);
  merge2<8>(rp, rt, lane, a63);
  merge2<16>(rp, rt, lane, a63);
  merge2<32>(rp, rt, lane, a63);

  // ranks are matched at identical (lane, v) after both sorts
  float acc = 0.f;
#pragma unroll
  for (int v = 0; v < V; ++v) {
    const float d = rp[v] - rt[v];
    acc = fmaf(d, d, acc);
  }
#pragma unroll
  for (int off = 32; off > 0; off >>= 1) acc += __shfl_down(acc, off, 64);
  if (lane == 0) {
    unsafeAtomicAdd(out, acc * (1.0f / ((float)ROWS * (float)NCOL)));
  }
}

extern "C" void kernel_launch(void* const* d_in, const int* in_sizes, int n_in,
                              void* d_out, int out_size, void* d_ws, size_t ws_size,
                              hipStream_t stream) {
  const float* pred = (const float*)d_in[0];
  const float* targ = (const float*)d_in[1];
  float* out = (float*)d_out;

  hipMemsetAsync(out, 0, sizeof(float), stream);  // d_out is re-poisoned 0xAA
  sort_mse_kernel<<<ROWS / WPB, THREADS, 0, stream>>>(pred, targ, out);
}

// Round 5
// 256.656 us; speedup vs baseline: 1.0296x; 1.0296x over previous
//
#include <hip/hip_runtime.h>
#include <math.h>

#define ROWS 8192
#define NCOL 2048
#define V 32
#define WPB 4                 // waves (rows) per block
#define THREADS (WPB * 64)

// static compare-exchange: ascending, both indices compile-time
__device__ __forceinline__ void ce(float& a, float& b) {
  const float lo = fminf(a, b);
  const float hi = fmaxf(a, b);
  a = lo; b = hi;
}

// med3(a,b,-inf)=min(a,b); med3(a,b,+inf)=max(a,b). One VALU op per
// cross-lane compare-exchange, direction baked into per-pass constant.
__device__ __forceinline__ float ce_dir(float a, float b, float cdir) {
  return __builtin_amdgcn_fmed3f(a, b, cdir);
}

// ---- cross-lane partner fetch x[lane ^ M] ----
// ds_swizzle BitMode for all masks <= 31 (pattern is an immediate, zero VALU
// address overhead). Mask 63 uses ds_bpermute with an address VGPR computed
// once at entry.
template <int M>
__device__ __forceinline__ float lane_xor(float x, int a63) {
  if constexpr (M == 63) {
    return __builtin_bit_cast(
        float, __builtin_amdgcn_ds_bpermute(a63, __builtin_bit_cast(int, x)));
  } else {
    static_assert(M >= 1 && M <= 31, "swizzle mask");
    constexpr int pat = (M << 10) | 0x1F;  // BitMode: xor=M, or=0, and=0x1F
    return __builtin_bit_cast(
        float, __builtin_amdgcn_ds_swizzle(__builtin_bit_cast(int, x), pat));
  }
}

// cross-lane xor pass over ONE array, same element index, mask M.
// 8 independent DS ops in flight before each med3 batch.
template <int M>
__device__ __forceinline__ void xpass1(float (&x)[V], float cdir, int a63) {
#pragma unroll
  for (int c = 0; c < V; c += 8) {
    float o[8];
#pragma unroll
    for (int u = 0; u < 8; ++u) o[u] = lane_xor<M>(x[c + u], a63);
#pragma unroll
    for (int u = 0; u < 8; ++u) x[c + u] = ce_dir(x[c + u], o[u], cdir);
  }
}

// One bitonic merge stage for run length k = 64*KB (KB = 1..32), ONE array:
// flip pass (partner lane^(2KB-1), elem v^31), xor passes KB/2..1,
// then the in-lane tail j = 16..1.
template <int KB>
__device__ __forceinline__ void merge1(float (&x)[V], int lane, int a63) {
  {
    constexpr int LM = 2 * KB - 1;
    const float cdir = (lane & KB) ? INFINITY : -INFINITY;
#pragma unroll
    for (int q = 0; q < 4; ++q) {
      const int vA = 4 * q;
      float o[8];
#pragma unroll
      for (int u = 0; u < 4; ++u) {
        o[u]     = lane_xor<LM>(x[(vA + u) ^ 31], a63);
        o[u + 4] = lane_xor<LM>(x[vA + u], a63);
      }
#pragma unroll
      for (int u = 0; u < 4; ++u) {
        x[vA + u]        = ce_dir(x[vA + u],        o[u],     cdir);
        x[(vA + u) ^ 31] = ce_dir(x[(vA + u) ^ 31], o[u + 4], cdir);
      }
    }
  }
  if constexpr (KB >= 32) xpass1<16>(x, (lane & 16) ? INFINITY : -INFINITY, a63);
  if constexpr (KB >= 16) xpass1<8>(x, (lane & 8) ? INFINITY : -INFINITY, a63);
  if constexpr (KB >= 8)  xpass1<4>(x, (lane & 4) ? INFINITY : -INFINITY, a63);
  if constexpr (KB >= 4)  xpass1<2>(x, (lane & 2) ? INFINITY : -INFINITY, a63);
  if constexpr (KB >= 2)  xpass1<1>(x, (lane & 1) ? INFINITY : -INFINITY, a63);
  // in-lane xor passes j = 16..1: static indices AND static direction
#pragma unroll
  for (int j = 16; j >= 1; j >>= 1) {
#pragma unroll
    for (int v = 0; v < V; ++v) {
      if ((v & j) == 0) ce(x[v], x[v | j]);
    }
  }
}

// Full normalized bitonic sort of one 2048-run (32 values/lane x 64 lanes).
__device__ __forceinline__ void sort_one(float (&x)[V], int lane, int a63) {
  // ---- Phase 1: stages k = 2..32, fully in-lane, fully static ----
#pragma unroll
  for (int k = 2; k <= V; k <<= 1) {
#pragma unroll
    for (int v = 0; v < V; ++v) {
      if ((v & (k >> 1)) == 0) ce(x[v], x[v ^ (k - 1)]);
    }
#pragma unroll
    for (int j = k >> 2; j >= 1; j >>= 1) {
#pragma unroll
      for (int v = 0; v < V; ++v) {
        if ((v & j) == 0) ce(x[v], x[v | j]);
      }
    }
  }
  // ---- Phase 2: stages k = 64..2048 ----
  merge1<1>(x, lane, a63);
  merge1<2>(x, lane, a63);
  merge1<4>(x, lane, a63);
  merge1<8>(x, lane, a63);
  merge1<16>(x, lane, a63);
  merge1<32>(x, lane, a63);
}

// One wave per row; lane holds elements e = lane*32 + v of both arrays in
// registers.
//
// DE-INTERLEAVED sorts: rounds 0-4 interleaved rp/rt passes; the allocator
// keeps ~half the 64 live floats in AGPRs (VGPR_Count=40 even with a 256-reg
// budget - round 4 falsified the launch-bounds theory) and round-trips
// v_accvgpr_read/write around EVERY pass (~4k phantom VALU ops/wave, the
// measured ~2x VALU inflation). Sorting rp fully, then rt fully, makes the
// cold array's AGPR residency free: traffic only at the two boundaries.
__global__ __launch_bounds__(THREADS, 2) void sort_mse_kernel(
    const float* __restrict__ pred, const float* __restrict__ targ,
    float* __restrict__ out) {
  const int lane = threadIdx.x & 63;
  const int wave = threadIdx.x >> 6;
  const int row = blockIdx.x * WPB + wave;
  const size_t base = (size_t)row * NCOL + (size_t)lane * V;
  const int a63 = ((lane ^ 63) << 2);  // bpermute byte addr, computed once

  float rp[V], rt[V];
  const float4* p4 = (const float4*)(pred + base);
  const float4* t4 = (const float4*)(targ + base);
#pragma unroll
  for (int q = 0; q < V / 4; ++q) {
    const float4 a = p4[q];
    rp[4 * q + 0] = a.x; rp[4 * q + 1] = a.y;
    rp[4 * q + 2] = a.z; rp[4 * q + 3] = a.w;
    const float4 b = t4[q];
    rt[4 * q + 0] = b.x; rt[4 * q + 1] = b.y;
    rt[4 * q + 2] = b.z; rt[4 * q + 3] = b.w;
  }

  sort_one(rp, lane, a63);   // rt cold (AGPR-resident, zero traffic)
  sort_one(rt, lane, a63);   // rp cold

  // ranks are matched at identical (lane, v) after both sorts
  float acc = 0.f;
#pragma unroll
  for (int v = 0; v < V; ++v) {
    const float d = rp[v] - rt[v];
    acc = fmaf(d, d, acc);
  }
#pragma unroll
  for (int off = 32; off > 0; off >>= 1) acc += __shfl_down(acc, off, 64);
  if (lane == 0) {
    unsafeAtomicAdd(out, acc * (1.0f / ((float)ROWS * (float)NCOL)));
  }
}

extern "C" void kernel_launch(void* const* d_in, const int* in_sizes, int n_in,
                              void* d_out, int out_size, void* d_ws, size_t ws_size,
                              hipStream_t stream) {
  const float* pred = (const float*)d_in[0];
  const float* targ = (const float*)d_in[1];
  float* out = (float*)d_out;

  hipMemsetAsync(out, 0, sizeof(float), stream);  // d_out is re-poisoned 0xAA
  sort_mse_kernel<<<ROWS / WPB, THREADS, 0, stream>>>(pred, targ, out);
}

// Round 6
// 241.628 us; speedup vs baseline: 1.0936x; 1.0622x over previous
//
#include <hip/hip_runtime.h>
#include <math.h>

#define ROWS 8192
#define NCOL 2048
#define V 32
#define WPB 4                 // waves (rows) per block
#define THREADS (WPB * 64)

// static compare-exchange: ascending, both indices compile-time
__device__ __forceinline__ void ce(float& a, float& b) {
  const float lo = fminf(a, b);
  const float hi = fmaxf(a, b);
  a = lo; b = hi;
}

// med3(a,b,-inf)=min(a,b); med3(a,b,+inf)=max(a,b). One VALU op per
// cross-lane compare-exchange, direction in a per-pass runtime constant.
__device__ __forceinline__ float ce_dir(float a, float b, float cdir) {
  return __builtin_amdgcn_fmed3f(a, b, cdir);
}

// runtime-mask cross-lane fetch: dest lane gets src lane (addr>>2)&63.
__device__ __forceinline__ float bperm(int addr, float x) {
  return __builtin_bit_cast(
      float, __builtin_amdgcn_ds_bpermute(addr, __builtin_bit_cast(int, x)));
}

// Full normalized bitonic sort of one 2048-run (32 values/lane x 64 lanes).
//
// CODE-SIZE-FIRST structure: rounds 0-5 fully unrolled all 66 passes into
// ~10-15k straight-line instructions (~100 KB). Each instr executes ONCE per
// wave -> zero I-cache reuse -> front-end fetch-bound; that's why every
// pipe-rebalancing experiment (DPP vs swizzle vs bpermute, launch bounds,
// de-interleave) landed at the same 150-167 us with all pipes <45% busy.
// Here Phase 2 is a real runtime loop (6 iterations, ~2.6 KB body): masks
// become runtime bpermute addresses; element indices stay compile-time.
__device__ __forceinline__ void sort_one(float (&x)[V], int lane) {
  // ---- Phase 1: stages k = 2..32, fully in-lane, fully static ----
#pragma unroll
  for (int k = 2; k <= V; k <<= 1) {
#pragma unroll
    for (int v = 0; v < V; ++v) {
      if ((v & (k >> 1)) == 0) ce(x[v], x[v ^ (k - 1)]);
    }
#pragma unroll
    for (int j = k >> 2; j >= 1; j >>= 1) {
#pragma unroll
      for (int v = 0; v < V; ++v) {
        if ((v & j) == 0) ce(x[v], x[v | j]);
      }
    }
  }

  // ---- Phase 2: merge stages k = 64*kb, kb = 1..32 — ROLLED ----
#pragma unroll 1
  for (int kb = 1; kb <= 32; kb <<= 1) {
    // flip pass: partner lane^(2kb-1), partner elem v^31,
    // keep min iff (lane & kb) == 0
    {
      const int addr = ((lane ^ (2 * kb - 1)) << 2);
      const float cdir = (lane & kb) ? INFINITY : -INFINITY;
#pragma unroll
      for (int q = 0; q < 4; ++q) {
        const int vA = 4 * q;
        float o[8];
#pragma unroll
        for (int u = 0; u < 4; ++u) {
          o[u]     = bperm(addr, x[(vA + u) ^ 31]);
          o[u + 4] = bperm(addr, x[vA + u]);
        }
#pragma unroll
        for (int u = 0; u < 4; ++u) {
          x[vA + u]        = ce_dir(x[vA + u],        o[u],     cdir);
          x[(vA + u) ^ 31] = ce_dir(x[(vA + u) ^ 31], o[u + 4], cdir);
        }
      }
    }
    // cross-lane xor passes: mask m = kb/2 .. 1, same element index,
    // keep min iff (lane & m) == 0
#pragma unroll 1
    for (int m = kb >> 1; m >= 1; m >>= 1) {
      const int addr = ((lane ^ m) << 2);
      const float cdir = (lane & m) ? INFINITY : -INFINITY;
#pragma unroll
      for (int c = 0; c < V; c += 8) {
        float o[8];
#pragma unroll
        for (int u = 0; u < 8; ++u) o[u] = bperm(addr, x[c + u]);
#pragma unroll
        for (int u = 0; u < 8; ++u) x[c + u] = ce_dir(x[c + u], o[u], cdir);
      }
    }
    // in-lane xor passes j = 16..1: static indices, static direction —
    // one copy of this code, shared by all 6 merge stages.
#pragma unroll
    for (int j = 16; j >= 1; j >>= 1) {
#pragma unroll
      for (int v = 0; v < V; ++v) {
        if ((v & j) == 0) ce(x[v], x[v | j]);
      }
    }
  }
}

// One wave per row; lane holds elements e = lane*32 + v of both arrays in
// registers. De-interleaved sorts keep the hot live set at ~40 regs so the
// cold array can sit in AGPRs with boundary-only traffic.
__global__ __launch_bounds__(THREADS, 2) void sort_mse_kernel(
    const float* __restrict__ pred, const float* __restrict__ targ,
    float* __restrict__ out) {
  const int lane = threadIdx.x & 63;
  const int wave = threadIdx.x >> 6;
  const int row = blockIdx.x * WPB + wave;
  const size_t base = (size_t)row * NCOL + (size_t)lane * V;

  float rp[V], rt[V];
  const float4* p4 = (const float4*)(pred + base);
  const float4* t4 = (const float4*)(targ + base);
#pragma unroll
  for (int q = 0; q < V / 4; ++q) {
    const float4 a = p4[q];
    rp[4 * q + 0] = a.x; rp[4 * q + 1] = a.y;
    rp[4 * q + 2] = a.z; rp[4 * q + 3] = a.w;
    const float4 b = t4[q];
    rt[4 * q + 0] = b.x; rt[4 * q + 1] = b.y;
    rt[4 * q + 2] = b.z; rt[4 * q + 3] = b.w;
  }

  sort_one(rp, lane);   // rt cold
  sort_one(rt, lane);   // rp cold

  // ranks are matched at identical (lane, v) after both sorts
  float acc = 0.f;
#pragma unroll
  for (int v = 0; v < V; ++v) {
    const float d = rp[v] - rt[v];
    acc = fmaf(d, d, acc);
  }
#pragma unroll
  for (int off = 32; off > 0; off >>= 1) acc += __shfl_down(acc, off, 64);
  if (lane == 0) {
    unsafeAtomicAdd(out, acc * (1.0f / ((float)ROWS * (float)NCOL)));
  }
}

extern "C" void kernel_launch(void* const* d_in, const int* in_sizes, int n_in,
                              void* d_out, int out_size, void* d_ws, size_t ws_size,
                              hipStream_t stream) {
  const float* pred = (const float*)d_in[0];
  const float* targ = (const float*)d_in[1];
  float* out = (float*)d_out;

  hipMemsetAsync(out, 0, sizeof(float), stream);  // d_out is re-poisoned 0xAA
  sort_mse_kernel<<<ROWS / WPB, THREADS, 0, stream>>>(pred, targ, out);
}

// Round 7
// 233.914 us; speedup vs baseline: 1.1297x; 1.0330x over previous
//
#include <hip/hip_runtime.h>
#include <math.h>

#define ROWS 8192
#define NCOL 2048
#define V 32
#define THREADS 256           // 4 waves: w0,w1 sort pred rows; w2,w3 sort targ

// static compare-exchange: ascending, both indices compile-time
__device__ __forceinline__ void ce(float& a, float& b) {
  const float lo = fminf(a, b);
  const float hi = fmaxf(a, b);
  a = lo; b = hi;
}

// med3(a,b,-inf)=min(a,b); med3(a,b,+inf)=max(a,b). One VALU op per
// cross-lane compare-exchange, direction in a per-pass runtime constant.
__device__ __forceinline__ float ce_dir(float a, float b, float cdir) {
  return __builtin_amdgcn_fmed3f(a, b, cdir);
}

// runtime-mask cross-lane fetch: dest lane gets src lane (addr>>2)&63.
__device__ __forceinline__ float bperm(int addr, float x) {
  return __builtin_bit_cast(
      float, __builtin_amdgcn_ds_bpermute(addr, __builtin_bit_cast(int, x)));
}

// Full normalized bitonic sort of one 2048-run (32 values/lane x 64 lanes).
// Phase 2 rolled (round 6: keeps hot loop I-cache-resident).
__device__ __forceinline__ void sort_one(float (&x)[V], int lane) {
  // ---- Phase 1: stages k = 2..32, fully in-lane, fully static ----
#pragma unroll
  for (int k = 2; k <= V; k <<= 1) {
#pragma unroll
    for (int v = 0; v < V; ++v) {
      if ((v & (k >> 1)) == 0) ce(x[v], x[v ^ (k - 1)]);
    }
#pragma unroll
    for (int j = k >> 2; j >= 1; j >>= 1) {
#pragma unroll
      for (int v = 0; v < V; ++v) {
        if ((v & j) == 0) ce(x[v], x[v | j]);
      }
    }
  }

  // ---- Phase 2: merge stages k = 64*kb, kb = 1..32 — ROLLED ----
#pragma unroll 1
  for (int kb = 1; kb <= 32; kb <<= 1) {
    // flip pass: partner lane^(2kb-1), partner elem v^31,
    // keep min iff (lane & kb) == 0
    {
      const int addr = ((lane ^ (2 * kb - 1)) << 2);
      const float cdir = (lane & kb) ? INFINITY : -INFINITY;
#pragma unroll
      for (int q = 0; q < 4; ++q) {
        const int vA = 4 * q;
        float o[8];
#pragma unroll
        for (int u = 0; u < 4; ++u) {
          o[u]     = bperm(addr, x[(vA + u) ^ 31]);
          o[u + 4] = bperm(addr, x[vA + u]);
        }
#pragma unroll
        for (int u = 0; u < 4; ++u) {
          x[vA + u]        = ce_dir(x[vA + u],        o[u],     cdir);
          x[(vA + u) ^ 31] = ce_dir(x[(vA + u) ^ 31], o[u + 4], cdir);
        }
      }
    }
    // cross-lane xor passes: mask m = kb/2 .. 1, same element index
#pragma unroll 1
    for (int m = kb >> 1; m >= 1; m >>= 1) {
      const int addr = ((lane ^ m) << 2);
      const float cdir = (lane & m) ? INFINITY : -INFINITY;
#pragma unroll
      for (int c = 0; c < V; c += 8) {
        float o[8];
#pragma unroll
        for (int u = 0; u < 8; ++u) o[u] = bperm(addr, x[c + u]);
#pragma unroll
        for (int u = 0; u < 8; ++u) x[c + u] = ce_dir(x[c + u], o[u], cdir);
      }
    }
    // in-lane xor passes j = 16..1: static indices, static direction
#pragma unroll
    for (int j = 16; j >= 1; j >>= 1) {
#pragma unroll
      for (int v = 0; v < V; ++v) {
        if ((v & j) == 0) ce(x[v], x[v | j]);
      }
    }
  }
}

// OCCUPANCY-FIRST structure (round 7): rounds 0-6 held BOTH arrays per wave
// (~80 unified regs incl. AGPR-parked cold array) -> 3.4 waves/SIMD, and
// every pipe-mix experiment landed at 150-167 us with all pipes <50% busy
// (the 45% VALUBusy is a gfx94x SIMD-16 formula; real VALU issue ~21%).
// Lead theory: latency-bound on bperm->med3 chains with too few waves.
// Fix: ONE array per wave (live set ~50 regs, no AGPRs). Waves 0-1 sort two
// pred rows and keep them in regs; waves 2-3 sort the matching targ rows and
// publish via LDS; pred waves then run the identical fmaf epilogue.
__global__ __launch_bounds__(THREADS, 8) void sort_mse_kernel(
    const float* __restrict__ pred, const float* __restrict__ targ,
    float* __restrict__ out) {
  const int lane = threadIdx.x & 63;
  const int wave = threadIdx.x >> 6;
  const int pair = wave & 1;      // which of the block's 2 rows
  const int role = wave >> 1;     // 0 = pred (accumulate), 1 = targ (publish)
  const int row = blockIdx.x * 2 + pair;
  const size_t base = (size_t)row * NCOL + (size_t)lane * V;

  // 2 rows x 2048 floats = 16 KB; bank-swizzled access (see below)
  __shared__ float tbuf[2][NCOL];

  float x[V];
  const float4* s4 =
      (const float4*)((role ? targ : pred) + base);
#pragma unroll
  for (int q = 0; q < V / 4; ++q) {
    const float4 a = s4[q];
    x[4 * q + 0] = a.x; x[4 * q + 1] = a.y;
    x[4 * q + 2] = a.z; x[4 * q + 3] = a.w;
  }

  sort_one(x, lane);

  // targ waves publish sorted rows. Physical placement: logical word
  // (lane,v=4q+i) -> word lane*32 + 4*(q^(lane&7)) + i. The XOR on the
  // 16B-block index spreads each b128 op across all 32 banks (2 lanes/bank
  // = free); without it, all 64 lanes hit the same 4 banks (8x serialize).
  // Register indices stay compile-time (XOR applied to the ADDRESS only).
  if (role == 1) {
#pragma unroll
    for (int q = 0; q < V / 4; ++q) {
      const int w = lane * V + 4 * (q ^ (lane & 7));
      *(float4*)&tbuf[pair][w] =
          make_float4(x[4 * q + 0], x[4 * q + 1], x[4 * q + 2], x[4 * q + 3]);
    }
  }
  __syncthreads();
  if (role == 1) return;

  // pred waves: read partner's sorted row back in the SAME swizzled layout;
  // identical per-row fmaf order to rounds 0-6.
  float acc = 0.f;
#pragma unroll
  for (int q = 0; q < V / 4; ++q) {
    const int w = lane * V + 4 * (q ^ (lane & 7));
    const float4 t4 = *(const float4*)&tbuf[pair][w];
    float d;
    d = x[4 * q + 0] - t4.x; acc = fmaf(d, d, acc);
    d = x[4 * q + 1] - t4.y; acc = fmaf(d, d, acc);
    d = x[4 * q + 2] - t4.z; acc = fmaf(d, d, acc);
    d = x[4 * q + 3] - t4.w; acc = fmaf(d, d, acc);
  }
#pragma unroll
  for (int off = 32; off > 0; off >>= 1) acc += __shfl_down(acc, off, 64);
  if (lane == 0) {
    unsafeAtomicAdd(out, acc * (1.0f / ((float)ROWS * (float)NCOL)));
  }
}

extern "C" void kernel_launch(void* const* d_in, const int* in_sizes, int n_in,
                              void* d_out, int out_size, void* d_ws, size_t ws_size,
                              hipStream_t stream) {
  const float* pred = (const float*)d_in[0];
  const float* targ = (const float*)d_in[1];
  float* out = (float*)d_out;

  hipMemsetAsync(out, 0, sizeof(float), stream);  // d_out is re-poisoned 0xAA
  sort_mse_kernel<<<ROWS / 2, THREADS, 0, stream>>>(pred, targ, out);
}

// Round 8
// 233.397 us; speedup vs baseline: 1.1322x; 1.0022x over previous
//
#include <hip/hip_runtime.h>
#include <math.h>

#define ROWS 8192
#define NCOL 2048
#define V 32
#define THREADS 256           // 4 waves: w0,w1 sort pred rows; w2,w3 sort targ

// static compare-exchange: ascending, both indices compile-time
__device__ __forceinline__ void ce(float& a, float& b) {
  const float lo = fminf(a, b);
  const float hi = fmaxf(a, b);
  a = lo; b = hi;
}

// med3(a,b,-inf)=min(a,b); med3(a,b,+inf)=max(a,b).
__device__ __forceinline__ float ce_dir(float a, float b, float cdir) {
  return __builtin_amdgcn_fmed3f(a, b, cdir);
}

// ---- cross-lane partner fetch x[lane ^ M], cheapest primitive per mask ----
// Round-7 profile: DS pipe ~76% busy (672 bpermutes/wave), VALU ~23%.
// 15 of 21 cross-lane passes have exact DPP controls -> pure VALU, no
// lgkmcnt; 5 passes keep ds_swizzle (immediate pattern); 1 pass bpermute.
template <int CTRL>
__device__ __forceinline__ float dpp_mov(float x) {
  return __builtin_bit_cast(
      float, __builtin_amdgcn_update_dpp(0, __builtin_bit_cast(int, x),
                                         CTRL, 0xF, 0xF, true));
}

template <int PAT>
__device__ __forceinline__ float swz(float x) {
  return __builtin_bit_cast(
      float, __builtin_amdgcn_ds_swizzle(__builtin_bit_cast(int, x), PAT));
}

template <int M>
__device__ __forceinline__ float lane_xor(float x, int a63) {
  if constexpr (M == 1)       return dpp_mov<0xB1>(x);    // quad_perm [1,0,3,2]
  else if constexpr (M == 2)  return dpp_mov<0x4E>(x);    // quad_perm [2,3,0,1]
  else if constexpr (M == 3)  return dpp_mov<0x1B>(x);    // quad_perm [3,2,1,0]
  else if constexpr (M == 7)  return dpp_mov<0x141>(x);   // row_half_mirror
  else if constexpr (M == 8)  return dpp_mov<0x128>(x);   // row_ror:8 == xor-8
  else if constexpr (M == 15) return dpp_mov<0x140>(x);   // row_mirror
  else if constexpr (M == 4)  return swz<0x101F>(x);      // BitMode xor-4
  else if constexpr (M == 16) return swz<0x401F>(x);      // BitMode xor-16
  else if constexpr (M == 31) return swz<0x7C1F>(x);      // BitMode xor-31
  else {                                                  // M == 63: bpermute
    return __builtin_bit_cast(
        float, __builtin_amdgcn_ds_bpermute(a63, __builtin_bit_cast(int, x)));
  }
}

// cross-lane xor pass over one array, same element index, mask M.
template <int M>
__device__ __forceinline__ void xpass1(float (&x)[V], float cdir, int a63) {
#pragma unroll
  for (int c = 0; c < V; c += 8) {
    float o[8];
#pragma unroll
    for (int u = 0; u < 8; ++u) o[u] = lane_xor<M>(x[c + u], a63);
#pragma unroll
    for (int u = 0; u < 8; ++u) x[c + u] = ce_dir(x[c + u], o[u], cdir);
  }
}

// One bitonic merge stage for run length k = 64*KB (KB = 1..32):
// flip pass (partner lane^(2KB-1), elem v^31), xor passes KB/2..1,
// then the in-lane tail j = 16..1.
template <int KB>
__device__ __forceinline__ void merge1(float (&x)[V], int lane, int a63) {
  {
    constexpr int LM = 2 * KB - 1;
    const float cdir = (lane & KB) ? INFINITY : -INFINITY;
#pragma unroll
    for (int q = 0; q < 4; ++q) {
      const int vA = 4 * q;
      float o[8];
#pragma unroll
      for (int u = 0; u < 4; ++u) {
        o[u]     = lane_xor<LM>(x[(vA + u) ^ 31], a63);
        o[u + 4] = lane_xor<LM>(x[vA + u], a63);
      }
#pragma unroll
      for (int u = 0; u < 4; ++u) {
        x[vA + u]        = ce_dir(x[vA + u],        o[u],     cdir);
        x[(vA + u) ^ 31] = ce_dir(x[(vA + u) ^ 31], o[u + 4], cdir);
      }
    }
  }
  if constexpr (KB >= 32) xpass1<16>(x, (lane & 16) ? INFINITY : -INFINITY, a63);
  if constexpr (KB >= 16) xpass1<8>(x, (lane & 8) ? INFINITY : -INFINITY, a63);
  if constexpr (KB >= 8)  xpass1<4>(x, (lane & 4) ? INFINITY : -INFINITY, a63);
  if constexpr (KB >= 4)  xpass1<2>(x, (lane & 2) ? INFINITY : -INFINITY, a63);
  if constexpr (KB >= 2)  xpass1<1>(x, (lane & 1) ? INFINITY : -INFINITY, a63);
  // in-lane xor passes j = 16..1: static indices AND static direction
#pragma unroll
  for (int j = 16; j >= 1; j >>= 1) {
#pragma unroll
    for (int v = 0; v < V; ++v) {
      if ((v & j) == 0) ce(x[v], x[v | j]);
    }
  }
}

// Full normalized bitonic sort of one 2048-run (32 values/lane x 64 lanes).
__device__ __forceinline__ void sort_one(float (&x)[V], int lane, int a63) {
  // ---- Phase 1: stages k = 2..32, fully in-lane, fully static ----
#pragma unroll
  for (int k = 2; k <= V; k <<= 1) {
#pragma unroll
    for (int v = 0; v < V; ++v) {
      if ((v & (k >> 1)) == 0) ce(x[v], x[v ^ (k - 1)]);
    }
#pragma unroll
    for (int j = k >> 2; j >= 1; j >>= 1) {
#pragma unroll
      for (int v = 0; v < V; ++v) {
        if ((v & j) == 0) ce(x[v], x[v | j]);
      }
    }
  }
  // ---- Phase 2: stages k = 64..2048 ----
  merge1<1>(x, lane, a63);
  merge1<2>(x, lane, a63);
  merge1<4>(x, lane, a63);
  merge1<8>(x, lane, a63);
  merge1<16>(x, lane, a63);
  merge1<32>(x, lane, a63);
}

// Round-7 occupancy structure kept: ONE array per wave. Waves 0-1 sort pred
// rows (keep in regs); waves 2-3 sort matching targ rows, publish via LDS.
// __launch_bounds__(256,6): round 7's 8-wave cap (64 regs) pushed part of
// x[32] into AGPRs (VGPR_Count=32); 85-reg budget keeps it in pure VGPRs
// while LDS (16 KB/block) and regs still allow ~6-8 waves/SIMD.
__global__ __launch_bounds__(THREADS, 6) void sort_mse_kernel(
    const float* __restrict__ pred, const float* __restrict__ targ,
    float* __restrict__ out) {
  const int lane = threadIdx.x & 63;
  const int wave = threadIdx.x >> 6;
  const int pair = wave & 1;      // which of the block's 2 rows
  const int role = wave >> 1;     // 0 = pred (accumulate), 1 = targ (publish)
  const int row = blockIdx.x * 2 + pair;
  const size_t base = (size_t)row * NCOL + (size_t)lane * V;
  const int a63 = ((lane ^ 63) << 2);  // bpermute byte addr, computed once

  // 2 rows x 2048 floats = 16 KB; bank-swizzled access (see below)
  __shared__ float tbuf[2][NCOL];

  float x[V];
  const float4* s4 = (const float4*)((role ? targ : pred) + base);
#pragma unroll
  for (int q = 0; q < V / 4; ++q) {
    const float4 a = s4[q];
    x[4 * q + 0] = a.x; x[4 * q + 1] = a.y;
    x[4 * q + 2] = a.z; x[4 * q + 3] = a.w;
  }

  sort_one(x, lane, a63);

  // targ waves publish sorted rows. Physical placement: logical word
  // (lane,v=4q+i) -> word lane*32 + 4*(q^(lane&7)) + i; XOR on the 16B-block
  // index spreads each b128 op across all banks (2 lanes/bank = free).
  if (role == 1) {
#pragma unroll
    for (int q = 0; q < V / 4; ++q) {
      const int w = lane * V + 4 * (q ^ (lane & 7));
      *(float4*)&tbuf[pair][w] =
          make_float4(x[4 * q + 0], x[4 * q + 1], x[4 * q + 2], x[4 * q + 3]);
    }
  }
  __syncthreads();
  if (role == 1) return;

  // pred waves: read partner's sorted row back in the SAME swizzled layout.
  float acc = 0.f;
#pragma unroll
  for (int q = 0; q < V / 4; ++q) {
    const int w = lane * V + 4 * (q ^ (lane & 7));
    const float4 t4 = *(const float4*)&tbuf[pair][w];
    float d;
    d = x[4 * q + 0] - t4.x; acc = fmaf(d, d, acc);
    d = x[4 * q + 1] - t4.y; acc = fmaf(d, d, acc);
    d = x[4 * q + 2] - t4.z; acc = fmaf(d, d, acc);
    d = x[4 * q + 3] - t4.w; acc = fmaf(d, d, acc);
  }
#pragma unroll
  for (int off = 32; off > 0; off >>= 1) acc += __shfl_down(acc, off, 64);
  if (lane == 0) {
    unsafeAtomicAdd(out, acc * (1.0f / ((float)ROWS * (float)NCOL)));
  }
}

extern "C" void kernel_launch(void* const* d_in, const int* in_sizes, int n_in,
                              void* d_out, int out_size, void* d_ws, size_t ws_size,
                              hipStream_t stream) {
  const float* pred = (const float*)d_in[0];
  const float* targ = (const float*)d_in[1];
  float* out = (float*)d_out;

  hipMemsetAsync(out, 0, sizeof(float), stream);  // d_out is re-poisoned 0xAA
  sort_mse_kernel<<<ROWS / 2, THREADS, 0, stream>>>(pred, targ, out);
}